// Round 9
// baseline (262.652 us; speedup 1.0000x reference)
//
#include <hip/hip_runtime.h>
#include <math.h>

#define B_ 8192
#define D_ 4096
#define K_ 64
#define EPSF 1e-8f
#define LN2F 0.69314718056f
#define ENT_GRID 4096
#define NSPLIT 8

typedef float f32x4 __attribute__((ext_vector_type(4)));

// ---------------- kernels ----------------

// zero counts[64] + sd1[64] + sd8[64] (contiguous 192 words)
__global__ void k_init(int* __restrict__ z) {
  if (threadIdx.x < 192) z[threadIdx.x] = 0;
}

// one wave per row; K_ == 64 == wavefront: one coalesced read + ballot
__global__ void k_labels(const float* __restrict__ probs, int* __restrict__ labels,
                         int* __restrict__ counts, int* __restrict__ rowlist) {
  int row = blockIdx.x * 4 + (threadIdx.x >> 6);
  int lane = threadIdx.x & 63;
  float p = probs[(size_t)row * K_ + lane];
  unsigned long long m = __ballot(p > 0.5f);
  if (lane == 0) {
    int k = __ffsll(m) - 1;
    if (k >= 0) {
      labels[row] = k;
      int pos = atomicAdd(&counts[k], 1);
      rowlist[k * B_ + pos] = row;
    }
  }
}

// block per row, SEQUENTIAL rows: w = 1/max(||a||,eps); diag into sd[class],
// one atomic per block at the end (proven ~6.4 TB/s shape from r1-r3).
__global__ __launch_bounds__(256) void k_norms(const float* __restrict__ acts,
                                               const int* __restrict__ labels,
                                               float* __restrict__ wout,
                                               float* __restrict__ sd) {
  __shared__ float lds[4];
  int row = blockIdx.x;
  const f32x4* rp = (const f32x4*)(acts + (size_t)row * D_);
  int t = threadIdx.x;
  f32x4 v0 = rp[t];
  f32x4 v1 = rp[t + 256];
  f32x4 v2 = rp[t + 512];
  f32x4 v3 = rp[t + 768];
  float s = v0.x * v0.x + v0.y * v0.y + v0.z * v0.z + v0.w * v0.w;
  s += v1.x * v1.x + v1.y * v1.y + v1.z * v1.z + v1.w * v1.w;
  s += v2.x * v2.x + v2.y * v2.y + v2.z * v2.z + v2.w * v2.w;
  s += v3.x * v3.x + v3.y * v3.y + v3.z * v3.z + v3.w * v3.w;
#pragma unroll
  for (int o = 32; o > 0; o >>= 1) s += __shfl_down(s, o);
  if ((t & 63) == 0) lds[t >> 6] = s;
  __syncthreads();
  if (t == 0) {
    s = lds[0] + lds[1] + lds[2] + lds[3];
    float w = 1.0f / fmaxf(sqrtf(s), EPSF);
    wout[row] = w;
    atomicAdd(&sd[labels[row]], s * w * w);
  }
}

// gather classsum, r1 shape: block=(split<<8 | cc<<6 | k), 4-row unroll,
// NO per-row reduce/barrier -> deep MLP. Plain loads (want L3 hits).
__global__ __launch_bounds__(256) void k_classsum(const float* __restrict__ acts,
                                                  const int* __restrict__ counts,
                                                  const int* __restrict__ rowlist,
                                                  const float* __restrict__ warr,
                                                  float* __restrict__ Cpart) {
  int bid = blockIdx.x;
  int k = bid & 63;
  int cc = (bid >> 6) & 3;
  int split = bid >> 8;  // 0..NSPLIT-1
  int cnt = counts[k];
  int beg = (cnt * split) / NSPLIT;
  int end = (cnt * (split + 1)) / NSPLIT;
  int col = cc * 1024 + 4 * threadIdx.x;
  const int* rl = rowlist + k * B_;
  f32x4 acc0 = 0.f, acc1 = 0.f, acc2 = 0.f, acc3 = 0.f;
  int r = beg;
  for (; r + 4 <= end; r += 4) {
    int row0 = rl[r], row1 = rl[r + 1], row2 = rl[r + 2], row3 = rl[r + 3];
    float w0 = warr[row0], w1 = warr[row1], w2 = warr[row2], w3 = warr[row3];
    f32x4 v0 = *(const f32x4*)(acts + (size_t)row0 * D_ + col);
    f32x4 v1 = *(const f32x4*)(acts + (size_t)row1 * D_ + col);
    f32x4 v2 = *(const f32x4*)(acts + (size_t)row2 * D_ + col);
    f32x4 v3 = *(const f32x4*)(acts + (size_t)row3 * D_ + col);
    acc0 += w0 * v0;
    acc1 += w1 * v1;
    acc2 += w2 * v2;
    acc3 += w3 * v3;
  }
  for (; r < end; ++r) {
    int row0 = rl[r];
    float w0 = warr[row0];
    f32x4 v0 = *(const f32x4*)(acts + (size_t)row0 * D_ + col);
    acc0 += w0 * v0;
  }
  acc0 += acc1 + acc2 + acc3;
  *(f32x4*)(Cpart + ((size_t)split * K_ + k) * D_ + col) = acc0;
}

// mSm partials: 512 blocks; b<256 -> tensor1, else tensor8. k=b>>2, quarter q=b&3.
__global__ __launch_bounds__(256) void k_msm(const float* __restrict__ Cpart1,
                                             const float* __restrict__ Cpart8,
                                             float* __restrict__ msp1,
                                             float* __restrict__ msp8) {
  __shared__ float lds[4];
  int b = blockIdx.x;
  const float* Cpart = (b < 256) ? Cpart1 : Cpart8;
  float* msp = (b < 256) ? msp1 : msp8;
  b &= 255;
  int k = b >> 2;
  int q = b & 3;
  int t = threadIdx.x;
  int col = q * 1024 + 4 * t;
  f32x4 c = 0.f;
#pragma unroll
  for (int s = 0; s < NSPLIT; ++s)
    c += *(const f32x4*)(Cpart + ((size_t)s * K_ + k) * D_ + col);
  float sq = c.x * c.x + c.y * c.y + c.z * c.z + c.w * c.w;
#pragma unroll
  for (int o = 32; o > 0; o >>= 1) sq += __shfl_down(sq, o);
  if ((t & 63) == 0) lds[t >> 6] = sq;
  __syncthreads();
  if (t == 0) msp[blockIdx.x & 255] = lds[0] + lds[1] + lds[2] + lds[3];
}

__device__ __forceinline__ float ent1(float p) {
  p = fminf(fmaxf(p, EPSF), 1.0f - EPSF);
  float q = 1.0f - p;
  float lp = __builtin_amdgcn_logf(p);  // v_log_f32: log2
  float lq = __builtin_amdgcn_logf(fmaxf(q, 1e-38f));
  return -(p * lp + q * lq);
}

__device__ __forceinline__ float ent4(f32x4 v) {
  return ent1(v.x) + ent1(v.y) + ent1(v.z) + ent1(v.w);
}

// binary entropy over both masks; plain loads, 16 in flight, contiguous 32KB chunks
__global__ __launch_bounds__(256) void k_entropy(const f32x4* __restrict__ m1,
                                                 const f32x4* __restrict__ m8,
                                                 double* __restrict__ entpart) {
  __shared__ float lds[8];
  const int CHUNK = (B_ * D_ / 4) / ENT_GRID;  // 2048 f32x4 per block per mask
  int base = blockIdx.x * CHUNK;
  int t = threadIdx.x;
  float s1 = 0.f, s8 = 0.f;
  f32x4 a[8], b[8];
#pragma unroll
  for (int j = 0; j < 8; ++j) {
    int idx = base + t + j * 256;
    a[j] = m1[idx];
    b[j] = m8[idx];
  }
#pragma unroll
  for (int j = 0; j < 8; ++j) {
    s1 += ent4(a[j]);
    s8 += ent4(b[j]);
  }
#pragma unroll
  for (int o = 32; o > 0; o >>= 1) {
    s1 += __shfl_down(s1, o);
    s8 += __shfl_down(s8, o);
  }
  int wid = t >> 6;
  if ((t & 63) == 0) { lds[wid] = s1; lds[4 + wid] = s8; }
  __syncthreads();
  if (t == 0) {
    float t1 = lds[0] + lds[1] + lds[2] + lds[3];
    float t8 = lds[4] + lds[5] + lds[6] + lds[7];
    entpart[blockIdx.x]            = (double)(t1 * LN2F);
    entpart[ENT_GRID + blockIdx.x] = (double)(t8 * LN2F);
  }
}

__global__ void k_final(const double* __restrict__ entpart, const int* __restrict__ counts,
                        const float* __restrict__ sd1, const float* __restrict__ sd8,
                        const float* __restrict__ msp1, const float* __restrict__ msp8,
                        float* __restrict__ out) {
  __shared__ double dl[8];
  int t = threadIdx.x;
  double e1 = 0.0, e8 = 0.0;
  for (int i = t; i < ENT_GRID; i += 256) {
    e1 += entpart[i];
    e8 += entpart[ENT_GRID + i];
  }
#pragma unroll
  for (int o = 32; o > 0; o >>= 1) {
    e1 += __shfl_down(e1, o);
    e8 += __shfl_down(e8, o);
  }
  int wid = t >> 6;
  if ((t & 63) == 0) { dl[wid] = e1; dl[4 + wid] = e8; }
  __syncthreads();
  float pcm1 = 0.f, pcm8 = 0.f, valid = 0.f;
  if (t < K_) {
    float mSm1 = msp1[t * 4] + msp1[t * 4 + 1] + msp1[t * 4 + 2] + msp1[t * 4 + 3];
    float mSm8 = msp8[t * 4] + msp8[t * 4 + 1] + msp8[t * 4 + 2] + msp8[t * 4 + 3];
    float n = (float)counts[t];
    bool v = (n >= 2.0f);
    float np = fmaxf(0.5f * n * (n - 1.0f), 1.0f);
    valid = v ? 1.0f : 0.f;
    pcm1 = v ? 0.5f * (mSm1 - sd1[t]) / np : 0.f;
    pcm8 = v ? 0.5f * (mSm8 - sd8[t]) / np : 0.f;
  }
#pragma unroll
  for (int o = 32; o > 0; o >>= 1) {
    pcm1 += __shfl_down(pcm1, o);
    pcm8 += __shfl_down(pcm8, o);
    valid += __shfl_down(valid, o);
  }
  if (t == 0) {
    double etot1 = dl[0] + dl[1] + dl[2] + dl[3];
    double etot8 = dl[4] + dl[5] + dl[6] + dl[7];
    float sp1 = (float)(etot1 / (double)((long long)B_ * D_));
    float sp8 = (float)(etot8 / (double)((long long)B_ * D_));
    float cs1 = (valid > 0.f) ? pcm1 / fmaxf(valid, 1.0f) : 0.f;
    float cs8 = (valid > 0.f) ? pcm8 / fmaxf(valid, 1.0f) : 0.f;
    float sim1 = -cs1, sim8 = -cs8;
    out[0] = sim1 + sim8 + 0.001f * (sp1 + sp8);
    out[1] = sim1;
    out[2] = sim8;
    out[3] = sp1;
    out[4] = sp8;
  }
}

// ---------------- launcher ----------------
// ws layout (bytes):
//   0        : double entpart[2][4096]      65536
//   65536    : int    labels[B]             32768
//   98304    : int    counts[64]            256  \
//   98560    : float  sd1[64]               256   } zeroed together (192 words)
//   98816    : float  sd8[64]               256  /
//   99072    : float  msp1[256]             1024
//   100096   : float  msp8[256]             1024
//   102400   : float  w1[B]                 32768
//   135168   : float  w8[B]                 32768
//   167936   : int    rowlist[K][B]         2097152
//   2265088  : float  Cpart1[8][K][D]       8388608
//   10653696 : float  Cpart8[8][K][D]       8388608
//   total ~19 MB (ws_size observed ~539 MB)

extern "C" void kernel_launch(void* const* d_in, const int* in_sizes, int n_in,
                              void* d_out, int out_size, void* d_ws, size_t ws_size,
                              hipStream_t stream) {
  const float* probs = (const float*)d_in[0];
  const float* a1 = (const float*)d_in[1];
  const float* a8 = (const float*)d_in[2];
  const float* m1 = (const float*)d_in[3];
  const float* m8 = (const float*)d_in[4];
  float* out = (float*)d_out;
  char* ws = (char*)d_ws;

  double* entpart = (double*)(ws + 0);
  int* labels = (int*)(ws + 65536);
  int* counts = (int*)(ws + 98304);
  float* sd1 = (float*)(ws + 98560);
  float* sd8 = (float*)(ws + 98816);
  float* msp1 = (float*)(ws + 99072);
  float* msp8 = (float*)(ws + 100096);
  float* w1 = (float*)(ws + 102400);
  float* w8 = (float*)(ws + 135168);
  int* rowlist = (int*)(ws + 167936);
  float* Cpart1 = (float*)(ws + 2265088);
  float* Cpart8 = (float*)(ws + 10653696);

  k_init<<<1, 256, 0, stream>>>(counts);
  k_labels<<<B_ / 4, 256, 0, stream>>>(probs, labels, counts, rowlist);
  // per-tensor pairing: classsum re-reads the tensor norms just pulled into L3
  k_norms<<<B_, 256, 0, stream>>>(a1, labels, w1, sd1);
  k_classsum<<<K_ * 4 * NSPLIT, 256, 0, stream>>>(a1, counts, rowlist, w1, Cpart1);
  k_norms<<<B_, 256, 0, stream>>>(a8, labels, w8, sd8);
  k_classsum<<<K_ * 4 * NSPLIT, 256, 0, stream>>>(a8, counts, rowlist, w8, Cpart8);
  k_entropy<<<ENT_GRID, 256, 0, stream>>>((const f32x4*)m1, (const f32x4*)m8, entpart);
  k_msm<<<512, 256, 0, stream>>>(Cpart1, Cpart8, msp1, msp8);
  k_final<<<1, 256, 0, stream>>>(entpart, counts, sd1, sd8, msp1, msp8, out);
}